// Round 17
// baseline (256.012 us; speedup 1.0000x reference)
//
#include <hip/hip_runtime.h>
#include <stdint.h>

typedef unsigned short ushort_t;

#define KK3 3
#define IC 32      // input capsules
#define IP 16      // input pose
#define OC 32      // output capsules
#define OP 16      // output pose
#define NI 288     // KK3*KK3*IC (im2col "i" dimension)
#define HH 12
#define WWW 12
#define NTOT 1152  // b*h*w
#define CQ 512     // OC*OP
#define EPSQ 1e-9f
#define RWAVES 4   // waves per route block (256 threads)
#define RSTEPS 36  // route i-steps per lane
#define NIP 144    // i-pairs (K=32 MFMA steps)
#define NIG 24     // i-groups for votes_s0 (12 i = 6 pairs each)
#define IPG 6      // pairs per i-group
#define SROW 132   // slab row stride (ushorts)
#define SPAR (16 * SROW)
#define SWAVE (2 * SPAR)

typedef __attribute__((ext_vector_type(8))) short bf16x8;
typedef __attribute__((ext_vector_type(4))) float f32x4;

__device__ __forceinline__ float bf_lo(unsigned u) { return __uint_as_float(u << 16); }
__device__ __forceinline__ float bf_hi(unsigned u) { return __uint_as_float(u & 0xffff0000u); }
__device__ __forceinline__ ushort_t f2bf(float f) {
    unsigned u = __float_as_uint(f);
    return (ushort_t)((u + 0x7fffu + ((u >> 16) & 1u)) >> 16);   // RNE
}

// ---------------------------------------------------------------------------
// Kernel P: pack W (f32) -> bf16 in MFMA-B-fragment layout.  (unchanged, R8)
// ---------------------------------------------------------------------------
__global__ __launch_bounds__(64) void pack_kernel(
    const float* __restrict__ W, ushort_t* __restrict__ Wp)
{
    const int blk = blockIdx.x;          // ip*32 + c
    const int ip = blk >> 5;
    const int c = blk & 31;
    const int l = threadIdx.x;
    const int i = ip * 2 + ((l >> 5) & 1);
    const int p0 = ((l >> 4) & 1) * 8;
    const int q = l & 15;
    const float* src = W + (((size_t)(i * 32 + c) * 16 + p0) * 16 + q);
    union { ushort_t s[8]; uint4 u4; } o;
#pragma unroll
    for (int j = 0; j < 8; ++j) o.s[j] = f2bf(src[(size_t)j * 16]);
    *(uint4*)(Wp + ((size_t)blk * 64 + l) * 8) = o.u4;
}

// ---------------------------------------------------------------------------
// Kernel V (v4, NIG=24): votes + s0 partials via MFMA; wave-private LDS
// transpose.  (unchanged from R15)
// ---------------------------------------------------------------------------
__global__ __launch_bounds__(256) void votes_s0_kernel(
    const float* __restrict__ x, const ushort_t* __restrict__ Wp,
    ushort_t* __restrict__ votes, float* __restrict__ s0_part,
    int nStart, int nCount)
{
    __shared__ ushort_t slab[4 * SWAVE];   // 33792 B, wave-private quarters

    const int t = threadIdx.x;
    const int w = t >> 6;                // wave 0..3: owns ct = w*8 .. +8
    const int l = t & 63;
    const int pxt = blockIdx.x;
    const int ig = blockIdx.y;

    const int n = nStart + pxt * 16 + (l & 15);
    const int b = n / (HH * WWW);
    const int rem = n % (HH * WWW);
    const int y = rem / WWW;
    const int xx = rem % WWW;
    const int ioff = (l >> 5) & 1;
    const int p0 = ((l >> 4) & 1) * 8;

    const int q = l & 15;
    const int r0 = (l >> 4) * 4;
    const int j16 = l & 15;
    const int g4 = l >> 4;

    ushort_t* const myslab = slab + w * SWAVE;

    const bf16x8 z8 = {0, 0, 0, 0, 0, 0, 0, 0};
    const f32x4 z4 = {0.f, 0.f, 0.f, 0.f};

    f32x4 accs0[8];
#pragma unroll
    for (int ctl = 0; ctl < 8; ++ctl) accs0[ctl] = z4;

    for (int m = 0; m < IPG; ++m) {
        const int ip = ig * IPG + m;
        union { ushort_t s[8]; bf16x8 v; } ua;
        {
            const int i = ip * 2 + ioff;
            const int ky = i / (KK3 * IC);
            const int kx = (i / IC) % KK3;
            const int ic = i & (IC - 1);
            const int sy = y + ky - 1;
            const int sx = xx + kx - 1;
            if (sy >= 0 && sy < HH && sx >= 0 && sx < WWW) {
                const float* s = x + ((((size_t)b * HH + sy) * WWW + sx) * IC + ic) * IP + p0;
                const float4 v0 = *(const float4*)s;
                const float4 v1 = *(const float4*)(s + 4);
                ua.s[0] = f2bf(v0.x); ua.s[1] = f2bf(v0.y); ua.s[2] = f2bf(v0.z); ua.s[3] = f2bf(v0.w);
                ua.s[4] = f2bf(v1.x); ua.s[5] = f2bf(v1.y); ua.s[6] = f2bf(v1.z); ua.s[7] = f2bf(v1.w);
            } else {
#pragma unroll
                for (int j = 0; j < 8; ++j) ua.s[j] = 0;
            }
        }

#pragma unroll
        for (int ctl = 0; ctl < 8; ++ctl) {
            const int ct = w * 8 + ctl;
            const bf16x8 frag = *(const bf16x8*)(Wp + (((size_t)ip * 32 + ct) * 64 + l) * 8);
            const bf16x8 be = (l < 32) ? frag : z8;   // keep k<16  -> i_even
            const bf16x8 bo = (l < 32) ? z8 : frag;   // keep k>=16 -> i_odd
            const f32x4 ve = __builtin_amdgcn_mfma_f32_16x16x32_bf16(ua.v, be, z4, 0, 0, 0);
            const f32x4 vo = __builtin_amdgcn_mfma_f32_16x16x32_bf16(ua.v, bo, z4, 0, 0, 0);
            accs0[ctl] = __builtin_amdgcn_mfma_f32_16x16x32_bf16(ua.v, frag, accs0[ctl], 0, 0, 0);
#pragma unroll
            for (int r = 0; r < 4; ++r) {
                myslab[(r0 + r) * SROW + ctl * 16 + q] = f2bf(ve[r]);
                myslab[SPAR + (r0 + r) * SROW + ctl * 16 + q] = f2bf(vo[r]);
            }
        }

#pragma unroll
        for (int s = 0; s < 2; ++s) {
#pragma unroll
            for (int h = 0; h < 4; ++h) {
                const int row = h * 4 + g4;
                const ushort_t* sp = myslab + s * SPAR + row * SROW + j16 * 8;
                const uint2 lo = *(const uint2*)sp;
                const uint2 hi = *(const uint2*)(sp + 4);
                ushort_t* dst = votes + ((size_t)(pxt * 16 + row) * NI + (2 * ip + s)) * CQ
                                + w * 128 + j16 * 8;
                uint4 o; o.x = lo.x; o.y = lo.y; o.z = hi.x; o.w = hi.y;
                *(uint4*)dst = o;
            }
        }
    }

    {
#pragma unroll
        for (int ctl = 0; ctl < 8; ++ctl) {
            const int cq = (w * 8 + ctl) * 16 + q;
#pragma unroll
            for (int r = 0; r < 4; ++r)
                s0_part[((size_t)ig * nCount + pxt * 16 + r0 + r) * CQ + cq] = accs0[ctl][r];
        }
    }
}

// ---------------------------------------------------------------------------
// Kernel F: s0_pre[bn][cq] = sum over NIG i-group partials.  (unchanged, R15)
// ---------------------------------------------------------------------------
__global__ __launch_bounds__(256) void s0_fin_kernel(
    const float* __restrict__ s0_part, float* __restrict__ s0_pre, int nCount)
{
    const int bn = blockIdx.x;
    const int t = threadIdx.x;
#pragma unroll
    for (int rep = 0; rep < 2; ++rep) {
        const int k = t + rep * 256;
        float s = 0.f;
#pragma unroll
        for (int g = 0; g < NIG; ++g)
            s += s0_part[((size_t)g * nCount + bn) * CQ + k];
        s0_pre[(size_t)bn * CQ + k] = s;
    }
}

// ---------------------------------------------------------------------------
// Kernel B (v5c): combined logits-free DR routing -- R15 structure with ONE
// change: the agreement dot is a TREE (depth 5) instead of a 16-deep serial
// FMA chain. R16 proved route is latency-chain-bound, not memory-bound
// (route-only dispatch: 103us with FETCH=25MB/L3-hot, VALUBusy 21%); the
// serial dot was the longest per-step dependency. +7 instrs, -11 levels.
// ---------------------------------------------------------------------------
#define UNPACK16(A, B)                                                     \
    const float f0 = bf_lo(A.x), f1 = bf_hi(A.x), f2 = bf_lo(A.y),         \
                f3 = bf_hi(A.y), f4 = bf_lo(A.z), f5 = bf_hi(A.z),         \
                f6 = bf_lo(A.w), f7 = bf_hi(A.w), f8 = bf_lo(B.x),         \
                f9 = bf_hi(B.x), f10 = bf_lo(B.y), f11 = bf_hi(B.y),       \
                f12 = bf_lo(B.z), f13 = bf_hi(B.z), f14 = bf_lo(B.w),      \
                f15 = bf_hi(B.w);

__global__ __launch_bounds__(256) void route_kernel(
    const ushort_t* __restrict__ votes, const float* __restrict__ s0_pre,
    const float* __restrict__ bias, float* __restrict__ out,
    int nStart, int nCount)
{
    __shared__ float sPart[RWAVES][CQ];   // 8 KB
    __shared__ float s_sh[CQ];            // 2 KB
    __shared__ float vcur_sh[CQ];         // 2 KB: v0, then v0+v1
    __shared__ float fac_sh[OC];
    __shared__ float pad_lds[5632];       // 22 KB anchor -> ~35 KB total:
                                          // 4 blocks/CU, VGPR budget 128

    const int bn = blockIdx.x;
    const int t = threadIdx.x;
    ((volatile float*)pad_lds)[t] = 0.f;  // keep the anchor allocated

    const int wv = t >> 6;
    const int l = t & 63;
    const int isub = l >> 5;
    const int c = l & 31;
    const int iBase = 2 * wv + isub;

    const ushort_t* pbase = votes + (size_t)bn * NI * CQ + (size_t)iBase * CQ + c * OP;
    const size_t stepB = (size_t)8 * CQ;

    // ---- phase 0: s0 from s0_pre -> v0
#pragma unroll
    for (int rep = 0; rep < 2; ++rep) {
        const int k = t + rep * 256;
        s_sh[k] = fmaf(s0_pre[(size_t)bn * CQ + k], 1.0f / OC, bias[k]);
    }
    __syncthreads();
    if (t < OC) {
        float sq = 0.f;
#pragma unroll
        for (int q = 0; q < OP; ++q) { const float s = s_sh[t * OP + q]; sq = fmaf(s, s, sq); }
        fac_sh[t] = (sq / (1.0f + sq)) * rsqrtf(sq + EPSQ);
    }
    __syncthreads();
#pragma unroll
    for (int rep = 0; rep < 2; ++rep) {
        const int k = t + rep * 256;
        vcur_sh[k] = s_sh[k] * fac_sh[k >> 4];
    }
    __syncthreads();

    float sa[16];
    float vr[16];

#define RBODY(AA, BB)                                                       \
        {                                                                   \
            UNPACK16(AA, BB)                                                \
            /* agreement dot: 8 parallel mul/fma pairs + 2-level add tree */ \
            const float d0 = fmaf(f1, vr[1], f0 * vr[0]);                   \
            const float d1 = fmaf(f3, vr[3], f2 * vr[2]);                   \
            const float d2 = fmaf(f5, vr[5], f4 * vr[4]);                   \
            const float d3 = fmaf(f7, vr[7], f6 * vr[6]);                   \
            const float d4 = fmaf(f9, vr[9], f8 * vr[8]);                   \
            const float d5 = fmaf(f11, vr[11], f10 * vr[10]);               \
            const float d6 = fmaf(f13, vr[13], f12 * vr[12]);               \
            const float d7 = fmaf(f15, vr[15], f14 * vr[14]);               \
            const float e0 = d0 + d1;                                       \
            const float e1 = d2 + d3;                                       \
            const float e2 = d4 + d5;                                       \
            const float e3 = d6 + d7;                                       \
            const float a = (e0 + e1) + (e2 + e3);                          \
            const float e = __expf(a);                                      \
            float es = e;                                                   \
            es += __shfl_xor(es, 1);                                        \
            es += __shfl_xor(es, 2);                                        \
            es += __shfl_xor(es, 4);                                        \
            es += __shfl_xor(es, 8);                                        \
            es += __shfl_xor(es, 16);                                       \
            const float coup = __fdividef(e, es);                           \
            sa[0] = fmaf(coup, f0, sa[0]);   sa[1] = fmaf(coup, f1, sa[1]); \
            sa[2] = fmaf(coup, f2, sa[2]);   sa[3] = fmaf(coup, f3, sa[3]); \
            sa[4] = fmaf(coup, f4, sa[4]);   sa[5] = fmaf(coup, f5, sa[5]); \
            sa[6] = fmaf(coup, f6, sa[6]);   sa[7] = fmaf(coup, f7, sa[7]); \
            sa[8] = fmaf(coup, f8, sa[8]);   sa[9] = fmaf(coup, f9, sa[9]); \
            sa[10] = fmaf(coup, f10, sa[10]); sa[11] = fmaf(coup, f11, sa[11]); \
            sa[12] = fmaf(coup, f12, sa[12]); sa[13] = fmaf(coup, f13, sa[13]); \
            sa[14] = fmaf(coup, f14, sa[14]); sa[15] = fmaf(coup, f15, sa[15]); \
        }
#define RPREF(AA, BB, rn)                                                   \
        if ((rn) < RSTEPS) {                                                \
            const uint4* pn = (const uint4*)(pbase + (size_t)(rn) * stepB); \
            AA = pn[0]; BB = pn[1];                                         \
        }

    // ---- 2 routed sweeps: A with vcur=v0, B with vcur=v0+v1
#pragma unroll
    for (int it = 0; it < 2; ++it) {
#pragma unroll
        for (int k = 0; k < 4; ++k) {
            const float4 v4 = *(const float4*)&vcur_sh[c * 16 + 4 * k];
            vr[4*k] = v4.x; vr[4*k+1] = v4.y; vr[4*k+2] = v4.z; vr[4*k+3] = v4.w;
        }
#pragma unroll
        for (int q = 0; q < 16; ++q) sa[q] = 0.f;

        uint4 A0, B0, A1, B1, A2, B2, A3, B3, A4, B4, A5, B5;
        RPREF(A0, B0, 0)
        RPREF(A1, B1, 1)
        RPREF(A2, B2, 2)
        RPREF(A3, B3, 3)
        RPREF(A4, B4, 4)
        RPREF(A5, B5, 5)
        for (int r = 0; r < RSTEPS; r += 6) {
            RBODY(A0, B0) RPREF(A0, B0, r + 6)
            RBODY(A1, B1) RPREF(A1, B1, r + 7)
            RBODY(A2, B2) RPREF(A2, B2, r + 8)
            RBODY(A3, B3) RPREF(A3, B3, r + 9)
            RBODY(A4, B4) RPREF(A4, B4, r + 10)
            RBODY(A5, B5) RPREF(A5, B5, r + 11)
        }

#pragma unroll
        for (int q = 0; q < 16; ++q) sa[q] += __shfl_xor(sa[q], 32);
        if (isub == 0) {
#pragma unroll
            for (int k = 0; k < 4; ++k)
                *(float4*)&sPart[wv][c * 16 + 4 * k] = make_float4(sa[4*k], sa[4*k+1], sa[4*k+2], sa[4*k+3]);
        }
        __syncthreads();
#pragma unroll
        for (int rep = 0; rep < 2; ++rep) {
            const int k = t + rep * 256;
            float s = (sPart[0][k] + sPart[1][k]) + (sPart[2][k] + sPart[3][k]);
            s_sh[k] = s + bias[k];
        }
        __syncthreads();
        if (t < OC) {
            float sq = 0.f;
#pragma unroll
            for (int q = 0; q < OP; ++q) { const float s = s_sh[t * OP + q]; sq = fmaf(s, s, sq); }
            fac_sh[t] = (sq / (1.0f + sq)) * rsqrtf(sq + EPSQ);
        }
        __syncthreads();
        if (it == 0) {
            // vcur <- v0 + v1 (the accumulated-logit direction)
#pragma unroll
            for (int rep = 0; rep < 2; ++rep) {
                const int k = t + rep * 256;
                vcur_sh[k] += s_sh[k] * fac_sh[k >> 4];
            }
            __syncthreads();
        } else {
            // final output v2
#pragma unroll
            for (int rep = 0; rep < 2; ++rep) {
                const int k = t + rep * 256;
                out[(size_t)(nStart + bn) * CQ + k] = s_sh[k] * fac_sh[k >> 4];
            }
        }
    }
}

// ---------------------------------------------------------------------------
extern "C" void kernel_launch(void* const* d_in, const int* in_sizes, int n_in,
                              void* d_out, int out_size, void* d_ws, size_t ws_size,
                              hipStream_t stream)
{
    const float* x = (const float*)d_in[0];
    const float* Wg = (const float*)d_in[1];
    const float* bias = (const float*)d_in[2];
    float* out = (float*)d_out;

    const size_t perN = (size_t)NI * CQ * sizeof(ushort_t);       // 294912 B/pixel
    const size_t packBytes = (size_t)NIP * 32 * 64 * 8 * 2;       // 4.72 MB
    const size_t perNpart = (size_t)NIG * CQ * sizeof(float);     // 49.2 KB/pixel partials
    const size_t perNpre = (size_t)CQ * sizeof(float);            // 2 KB/pixel s0_pre

    int chunk = 768;   // 226 MB votes chunk
    if (ws_size < (size_t)chunk * (perN + perNpart + perNpre) + packBytes) {
        size_t avail = (ws_size > packBytes) ? ws_size - packBytes : 0;
        chunk = (int)(avail / (perN + perNpart + perNpre));
        chunk &= ~15;
        if (chunk < 16) chunk = 16;
    }
    const size_t packOff = (size_t)chunk * perN;
    const size_t partOff = packOff + packBytes;
    const size_t preOff = partOff + (size_t)chunk * perNpart;

    ushort_t* votes = (ushort_t*)d_ws;
    ushort_t* Wp = (ushort_t*)((char*)d_ws + packOff);
    float* s0_part = (float*)((char*)d_ws + partOff);
    float* s0_pre = (float*)((char*)d_ws + preOff);

    hipLaunchKernelGGL(pack_kernel, dim3(NIP * 32), dim3(64), 0, stream, Wg, Wp);

    for (int start = 0; start < NTOT; start += chunk) {
        const int cnt = (NTOT - start < chunk) ? (NTOT - start) : chunk;
        hipLaunchKernelGGL(votes_s0_kernel, dim3(cnt / 16, NIG), dim3(256), 0, stream,
                           x, Wp, votes, s0_part, start, cnt);
        hipLaunchKernelGGL(s0_fin_kernel, dim3(cnt), dim3(256), 0, stream,
                           s0_part, s0_pre, cnt);
        hipLaunchKernelGGL(route_kernel, dim3(cnt), dim3(256), 0, stream,
                           votes, s0_pre, bias, out, start, cnt);
    }
}

// Round 18
// 221.460 us; speedup vs baseline: 1.1560x; 1.1560x over previous
//
#include <hip/hip_runtime.h>
#include <stdint.h>

typedef unsigned short ushort_t;

#define KK3 3
#define IC 32      // input capsules
#define IP 16      // input pose
#define OC 32      // output capsules
#define OP 16      // output pose
#define NI 288     // KK3*KK3*IC (im2col "i" dimension)
#define HH 12
#define WWW 12
#define NTOT 1152  // b*h*w
#define CQ 512     // OC*OP
#define EPSQ 1e-9f
#define RWAVES 4   // waves per route block (256 threads)
#define RSTEPS 36  // route i-steps per lane
#define NIP 144    // i-pairs (K=32 MFMA steps)
#define NIG 24     // i-groups for votes_s0 (12 i = 6 pairs each)
#define IPG 6      // pairs per i-group
#define SROW 132   // slab row stride (ushorts)
#define SPAR (16 * SROW)
#define SWAVE (2 * SPAR)

typedef __attribute__((ext_vector_type(8))) short bf16x8;
typedef __attribute__((ext_vector_type(4))) float f32x4;

__device__ __forceinline__ float bf_lo(unsigned u) { return __uint_as_float(u << 16); }
__device__ __forceinline__ float bf_hi(unsigned u) { return __uint_as_float(u & 0xffff0000u); }
__device__ __forceinline__ ushort_t f2bf(float f) {
    unsigned u = __float_as_uint(f);
    return (ushort_t)((u + 0x7fffu + ((u >> 16) & 1u)) >> 16);   // RNE
}

// ---------------------------------------------------------------------------
// Kernel P: pack W (f32) -> bf16 in MFMA-B-fragment layout.  (unchanged, R8)
// ---------------------------------------------------------------------------
__global__ __launch_bounds__(64) void pack_kernel(
    const float* __restrict__ W, ushort_t* __restrict__ Wp)
{
    const int blk = blockIdx.x;          // ip*32 + c
    const int ip = blk >> 5;
    const int c = blk & 31;
    const int l = threadIdx.x;
    const int i = ip * 2 + ((l >> 5) & 1);
    const int p0 = ((l >> 4) & 1) * 8;
    const int q = l & 15;
    const float* src = W + (((size_t)(i * 32 + c) * 16 + p0) * 16 + q);
    union { ushort_t s[8]; uint4 u4; } o;
#pragma unroll
    for (int j = 0; j < 8; ++j) o.s[j] = f2bf(src[(size_t)j * 16]);
    *(uint4*)(Wp + ((size_t)blk * 64 + l) * 8) = o.u4;
}

// ---------------------------------------------------------------------------
// Kernel V (v4, NIG=24): votes + s0 partials via MFMA; wave-private LDS
// transpose.  (unchanged from R15)
// ---------------------------------------------------------------------------
__global__ __launch_bounds__(256) void votes_s0_kernel(
    const float* __restrict__ x, const ushort_t* __restrict__ Wp,
    ushort_t* __restrict__ votes, float* __restrict__ s0_part,
    int nStart, int nCount)
{
    __shared__ ushort_t slab[4 * SWAVE];   // 33792 B, wave-private quarters

    const int t = threadIdx.x;
    const int w = t >> 6;                // wave 0..3: owns ct = w*8 .. +8
    const int l = t & 63;
    const int pxt = blockIdx.x;
    const int ig = blockIdx.y;

    const int n = nStart + pxt * 16 + (l & 15);
    const int b = n / (HH * WWW);
    const int rem = n % (HH * WWW);
    const int y = rem / WWW;
    const int xx = rem % WWW;
    const int ioff = (l >> 5) & 1;
    const int p0 = ((l >> 4) & 1) * 8;

    const int q = l & 15;
    const int r0 = (l >> 4) * 4;
    const int j16 = l & 15;
    const int g4 = l >> 4;

    ushort_t* const myslab = slab + w * SWAVE;

    const bf16x8 z8 = {0, 0, 0, 0, 0, 0, 0, 0};
    const f32x4 z4 = {0.f, 0.f, 0.f, 0.f};

    f32x4 accs0[8];
#pragma unroll
    for (int ctl = 0; ctl < 8; ++ctl) accs0[ctl] = z4;

    for (int m = 0; m < IPG; ++m) {
        const int ip = ig * IPG + m;
        union { ushort_t s[8]; bf16x8 v; } ua;
        {
            const int i = ip * 2 + ioff;
            const int ky = i / (KK3 * IC);
            const int kx = (i / IC) % KK3;
            const int ic = i & (IC - 1);
            const int sy = y + ky - 1;
            const int sx = xx + kx - 1;
            if (sy >= 0 && sy < HH && sx >= 0 && sx < WWW) {
                const float* s = x + ((((size_t)b * HH + sy) * WWW + sx) * IC + ic) * IP + p0;
                const float4 v0 = *(const float4*)s;
                const float4 v1 = *(const float4*)(s + 4);
                ua.s[0] = f2bf(v0.x); ua.s[1] = f2bf(v0.y); ua.s[2] = f2bf(v0.z); ua.s[3] = f2bf(v0.w);
                ua.s[4] = f2bf(v1.x); ua.s[5] = f2bf(v1.y); ua.s[6] = f2bf(v1.z); ua.s[7] = f2bf(v1.w);
            } else {
#pragma unroll
                for (int j = 0; j < 8; ++j) ua.s[j] = 0;
            }
        }

#pragma unroll
        for (int ctl = 0; ctl < 8; ++ctl) {
            const int ct = w * 8 + ctl;
            const bf16x8 frag = *(const bf16x8*)(Wp + (((size_t)ip * 32 + ct) * 64 + l) * 8);
            const bf16x8 be = (l < 32) ? frag : z8;   // keep k<16  -> i_even
            const bf16x8 bo = (l < 32) ? z8 : frag;   // keep k>=16 -> i_odd
            const f32x4 ve = __builtin_amdgcn_mfma_f32_16x16x32_bf16(ua.v, be, z4, 0, 0, 0);
            const f32x4 vo = __builtin_amdgcn_mfma_f32_16x16x32_bf16(ua.v, bo, z4, 0, 0, 0);
            accs0[ctl] = __builtin_amdgcn_mfma_f32_16x16x32_bf16(ua.v, frag, accs0[ctl], 0, 0, 0);
#pragma unroll
            for (int r = 0; r < 4; ++r) {
                myslab[(r0 + r) * SROW + ctl * 16 + q] = f2bf(ve[r]);
                myslab[SPAR + (r0 + r) * SROW + ctl * 16 + q] = f2bf(vo[r]);
            }
        }

#pragma unroll
        for (int s = 0; s < 2; ++s) {
#pragma unroll
            for (int h = 0; h < 4; ++h) {
                const int row = h * 4 + g4;
                const ushort_t* sp = myslab + s * SPAR + row * SROW + j16 * 8;
                const uint2 lo = *(const uint2*)sp;
                const uint2 hi = *(const uint2*)(sp + 4);
                ushort_t* dst = votes + ((size_t)(pxt * 16 + row) * NI + (2 * ip + s)) * CQ
                                + w * 128 + j16 * 8;
                uint4 o; o.x = lo.x; o.y = lo.y; o.z = hi.x; o.w = hi.y;
                *(uint4*)dst = o;
            }
        }
    }

    {
#pragma unroll
        for (int ctl = 0; ctl < 8; ++ctl) {
            const int cq = (w * 8 + ctl) * 16 + q;
#pragma unroll
            for (int r = 0; r < 4; ++r)
                s0_part[((size_t)ig * nCount + pxt * 16 + r0 + r) * CQ + cq] = accs0[ctl][r];
        }
    }
}

// ---------------------------------------------------------------------------
// Kernel F: s0_pre[bn][cq] = sum over NIG i-group partials.  (unchanged, R15)
// ---------------------------------------------------------------------------
__global__ __launch_bounds__(256) void s0_fin_kernel(
    const float* __restrict__ s0_part, float* __restrict__ s0_pre, int nCount)
{
    const int bn = blockIdx.x;
    const int t = threadIdx.x;
#pragma unroll
    for (int rep = 0; rep < 2; ++rep) {
        const int k = t + rep * 256;
        float s = 0.f;
#pragma unroll
        for (int g = 0; g < NIG; ++g)
            s += s0_part[((size_t)g * nCount + bn) * CQ + k];
        s0_pre[(size_t)bn * CQ + k] = s;
    }
}

// ---------------------------------------------------------------------------
// Kernel B (v5d): R15's logits-free route with ONE change: prefetch ring
// 6 -> 3 deep. Cross-round evidence: route@768 tracks register count /
// ring depth (R10-era 3-deep: <=73us; R12/R13/R15 6-deep: 88-92us; R17
// tree+6-deep VGPR132: 111us). At 12 waves/CU the memory pipe has enough
// outstanding loads without the extra depth; the 24 extra VGPRs only
// push toward the occupancy cliff. Dot stays the serial FMA chain
// (R17 proved the tree's VGPR cost exceeds its latency benefit).
// ---------------------------------------------------------------------------
#define UNPACK16(A, B)                                                     \
    const float f0 = bf_lo(A.x), f1 = bf_hi(A.x), f2 = bf_lo(A.y),         \
                f3 = bf_hi(A.y), f4 = bf_lo(A.z), f5 = bf_hi(A.z),         \
                f6 = bf_lo(A.w), f7 = bf_hi(A.w), f8 = bf_lo(B.x),         \
                f9 = bf_hi(B.x), f10 = bf_lo(B.y), f11 = bf_hi(B.y),       \
                f12 = bf_lo(B.z), f13 = bf_hi(B.z), f14 = bf_lo(B.w),      \
                f15 = bf_hi(B.w);

__global__ __launch_bounds__(256) void route_kernel(
    const ushort_t* __restrict__ votes, const float* __restrict__ s0_pre,
    const float* __restrict__ bias, float* __restrict__ out,
    int nStart, int nCount)
{
    __shared__ float sPart[RWAVES][CQ];   // 8 KB
    __shared__ float s_sh[CQ];            // 2 KB
    __shared__ float vcur_sh[CQ];         // 2 KB: v0, then v0+v1
    __shared__ float fac_sh[OC];
    __shared__ float pad_lds[5632];       // 22 KB anchor -> ~35 KB total:
                                          // pins allocator VGPR budget at 128

    const int bn = blockIdx.x;
    const int t = threadIdx.x;
    ((volatile float*)pad_lds)[t] = 0.f;  // keep the anchor allocated

    const int wv = t >> 6;
    const int l = t & 63;
    const int isub = l >> 5;
    const int c = l & 31;
    const int iBase = 2 * wv + isub;

    const ushort_t* pbase = votes + (size_t)bn * NI * CQ + (size_t)iBase * CQ + c * OP;
    const size_t stepB = (size_t)8 * CQ;

    // ---- phase 0: s0 from s0_pre -> v0
#pragma unroll
    for (int rep = 0; rep < 2; ++rep) {
        const int k = t + rep * 256;
        s_sh[k] = fmaf(s0_pre[(size_t)bn * CQ + k], 1.0f / OC, bias[k]);
    }
    __syncthreads();
    if (t < OC) {
        float sq = 0.f;
#pragma unroll
        for (int q = 0; q < OP; ++q) { const float s = s_sh[t * OP + q]; sq = fmaf(s, s, sq); }
        fac_sh[t] = (sq / (1.0f + sq)) * rsqrtf(sq + EPSQ);
    }
    __syncthreads();
#pragma unroll
    for (int rep = 0; rep < 2; ++rep) {
        const int k = t + rep * 256;
        vcur_sh[k] = s_sh[k] * fac_sh[k >> 4];
    }
    __syncthreads();

    float sa[16];
    float vr[16];

#define RBODY(AA, BB)                                                       \
        {                                                                   \
            UNPACK16(AA, BB)                                                \
            float a = f0 * vr[0];                                           \
            a = fmaf(f1, vr[1], a);   a = fmaf(f2, vr[2], a);               \
            a = fmaf(f3, vr[3], a);   a = fmaf(f4, vr[4], a);               \
            a = fmaf(f5, vr[5], a);   a = fmaf(f6, vr[6], a);               \
            a = fmaf(f7, vr[7], a);   a = fmaf(f8, vr[8], a);               \
            a = fmaf(f9, vr[9], a);   a = fmaf(f10, vr[10], a);             \
            a = fmaf(f11, vr[11], a); a = fmaf(f12, vr[12], a);             \
            a = fmaf(f13, vr[13], a); a = fmaf(f14, vr[14], a);             \
            a = fmaf(f15, vr[15], a);                                       \
            const float e = __expf(a);                                      \
            float es = e;                                                   \
            es += __shfl_xor(es, 1);                                        \
            es += __shfl_xor(es, 2);                                        \
            es += __shfl_xor(es, 4);                                        \
            es += __shfl_xor(es, 8);                                        \
            es += __shfl_xor(es, 16);                                       \
            const float coup = __fdividef(e, es);                           \
            sa[0] = fmaf(coup, f0, sa[0]);   sa[1] = fmaf(coup, f1, sa[1]); \
            sa[2] = fmaf(coup, f2, sa[2]);   sa[3] = fmaf(coup, f3, sa[3]); \
            sa[4] = fmaf(coup, f4, sa[4]);   sa[5] = fmaf(coup, f5, sa[5]); \
            sa[6] = fmaf(coup, f6, sa[6]);   sa[7] = fmaf(coup, f7, sa[7]); \
            sa[8] = fmaf(coup, f8, sa[8]);   sa[9] = fmaf(coup, f9, sa[9]); \
            sa[10] = fmaf(coup, f10, sa[10]); sa[11] = fmaf(coup, f11, sa[11]); \
            sa[12] = fmaf(coup, f12, sa[12]); sa[13] = fmaf(coup, f13, sa[13]); \
            sa[14] = fmaf(coup, f14, sa[14]); sa[15] = fmaf(coup, f15, sa[15]); \
        }
#define RPREF(AA, BB, rn)                                                   \
        if ((rn) < RSTEPS) {                                                \
            const uint4* pn = (const uint4*)(pbase + (size_t)(rn) * stepB); \
            AA = pn[0]; BB = pn[1];                                         \
        }

    // ---- 2 routed sweeps: A with vcur=v0, B with vcur=v0+v1
#pragma unroll
    for (int it = 0; it < 2; ++it) {
#pragma unroll
        for (int k = 0; k < 4; ++k) {
            const float4 v4 = *(const float4*)&vcur_sh[c * 16 + 4 * k];
            vr[4*k] = v4.x; vr[4*k+1] = v4.y; vr[4*k+2] = v4.z; vr[4*k+3] = v4.w;
        }
#pragma unroll
        for (int q = 0; q < 16; ++q) sa[q] = 0.f;

        uint4 A0, B0, A1, B1, A2, B2;      // 3-deep ring (R10 depth)
        RPREF(A0, B0, 0)
        RPREF(A1, B1, 1)
        RPREF(A2, B2, 2)
        for (int r = 0; r < RSTEPS; r += 3) {
            RBODY(A0, B0) RPREF(A0, B0, r + 3)
            RBODY(A1, B1) RPREF(A1, B1, r + 4)
            RBODY(A2, B2) RPREF(A2, B2, r + 5)
        }

#pragma unroll
        for (int q = 0; q < 16; ++q) sa[q] += __shfl_xor(sa[q], 32);
        if (isub == 0) {
#pragma unroll
            for (int k = 0; k < 4; ++k)
                *(float4*)&sPart[wv][c * 16 + 4 * k] = make_float4(sa[4*k], sa[4*k+1], sa[4*k+2], sa[4*k+3]);
        }
        __syncthreads();
#pragma unroll
        for (int rep = 0; rep < 2; ++rep) {
            const int k = t + rep * 256;
            float s = (sPart[0][k] + sPart[1][k]) + (sPart[2][k] + sPart[3][k]);
            s_sh[k] = s + bias[k];
        }
        __syncthreads();
        if (t < OC) {
            float sq = 0.f;
#pragma unroll
            for (int q = 0; q < OP; ++q) { const float s = s_sh[t * OP + q]; sq = fmaf(s, s, sq); }
            fac_sh[t] = (sq / (1.0f + sq)) * rsqrtf(sq + EPSQ);
        }
        __syncthreads();
        if (it == 0) {
            // vcur <- v0 + v1 (the accumulated-logit direction)
#pragma unroll
            for (int rep = 0; rep < 2; ++rep) {
                const int k = t + rep * 256;
                vcur_sh[k] += s_sh[k] * fac_sh[k >> 4];
            }
            __syncthreads();
        } else {
            // final output v2
#pragma unroll
            for (int rep = 0; rep < 2; ++rep) {
                const int k = t + rep * 256;
                out[(size_t)(nStart + bn) * CQ + k] = s_sh[k] * fac_sh[k >> 4];
            }
        }
    }
}

// ---------------------------------------------------------------------------
extern "C" void kernel_launch(void* const* d_in, const int* in_sizes, int n_in,
                              void* d_out, int out_size, void* d_ws, size_t ws_size,
                              hipStream_t stream)
{
    const float* x = (const float*)d_in[0];
    const float* Wg = (const float*)d_in[1];
    const float* bias = (const float*)d_in[2];
    float* out = (float*)d_out;

    const size_t perN = (size_t)NI * CQ * sizeof(ushort_t);       // 294912 B/pixel
    const size_t packBytes = (size_t)NIP * 32 * 64 * 8 * 2;       // 4.72 MB
    const size_t perNpart = (size_t)NIG * CQ * sizeof(float);     // 49.2 KB/pixel partials
    const size_t perNpre = (size_t)CQ * sizeof(float);            // 2 KB/pixel s0_pre

    int chunk = 768;   // 226 MB votes chunk
    if (ws_size < (size_t)chunk * (perN + perNpart + perNpre) + packBytes) {
        size_t avail = (ws_size > packBytes) ? ws_size - packBytes : 0;
        chunk = (int)(avail / (perN + perNpart + perNpre));
        chunk &= ~15;
        if (chunk < 16) chunk = 16;
    }
    const size_t packOff = (size_t)chunk * perN;
    const size_t partOff = packOff + packBytes;
    const size_t preOff = partOff + (size_t)chunk * perNpart;

    ushort_t* votes = (ushort_t*)d_ws;
    ushort_t* Wp = (ushort_t*)((char*)d_ws + packOff);
    float* s0_part = (float*)((char*)d_ws + partOff);
    float* s0_pre = (float*)((char*)d_ws + preOff);

    hipLaunchKernelGGL(pack_kernel, dim3(NIP * 32), dim3(64), 0, stream, Wg, Wp);

    for (int start = 0; start < NTOT; start += chunk) {
        const int cnt = (NTOT - start < chunk) ? (NTOT - start) : chunk;
        hipLaunchKernelGGL(votes_s0_kernel, dim3(cnt / 16, NIG), dim3(256), 0, stream,
                           x, Wp, votes, s0_part, start, cnt);
        hipLaunchKernelGGL(s0_fin_kernel, dim3(cnt), dim3(256), 0, stream,
                           s0_part, s0_pre, cnt);
        hipLaunchKernelGGL(route_kernel, dim3(cnt), dim3(256), 0, stream,
                           votes, s0_pre, bias, out, start, cnt);
    }
}